// Round 1
// baseline (824.147 us; speedup 1.0000x reference)
//
#include <hip/hip_runtime.h>
#include <math.h>

#define N_IMG 16
#define N_CLS 80
#define K_PRE 1000
#define K_POST 100
#define CAND 3000           // 3 levels * K_PRE
#define NPAIR 48            // N_IMG * 3

// ---- workspace layout (bytes) ----
#define HIST_OFF    0            // uint[48*256] = 49152
#define PREFIX_OFF  49152        // uint[48]
#define KK_OFF      49344        // uint[48]
#define CNTANY_OFF  49536        // uint[48]
#define CNTEQ_OFF   49728        // uint[48]
#define CANDF_OFF   49920        // uint[48000]
#define CANDS_OFF   241920       // float[48000]
#define DBOX_OFF    433920       // float4[48000]   (433920 % 16 == 0)
#define DSC_OFF     1201920      // float[48000]
#define DCLS_OFF    1393920      // int[48000]

__device__ __forceinline__ float sigm(float x) { return 1.0f / (1.0f + expf(-x)); }

__device__ __forceinline__ int lvl_hw(int lvl) { return lvl == 0 ? 10000 : (lvl == 1 ? 2500 : 625); }

__global__ void init_k(unsigned* hist, unsigned* prefix, unsigned* kk,
                       unsigned* cntAny, unsigned* cntEq, float* candS) {
    for (int i = blockIdx.x * blockDim.x + threadIdx.x; i < NPAIR * K_PRE;
         i += gridDim.x * blockDim.x) {
        if (i < NPAIR * 256) hist[i] = 0;
        if (i < NPAIR) { prefix[i] = 0; kk[i] = K_PRE; cntAny[i] = 0; cntEq[i] = 0; }
        candS[i] = -1.0f;
    }
}

// key for element i (i = c*HW + loc within one image's level)
__device__ __forceinline__ unsigned score_key(const float* clsI, const float* ctrI,
                                              int i, int HW, float* sc_out) {
    float cp = sigm(clsI[i]);
    if (cp > 0.05f) {
        int loc = i % HW;
        float sc = cp * sigm(ctrI[loc]);
        *sc_out = sc;
        return __float_as_uint(sc);   // sc in (0,1): positive-float bits are order-preserving
    }
    *sc_out = -1.0f;
    return 0u;
}

__global__ void histo_k(const float* cls0, const float* cls1, const float* cls2,
                        const float* ctr0, const float* ctr1, const float* ctr2,
                        unsigned* hist, const unsigned* prefix, int shift) {
    __shared__ unsigned lh[256];
    const int lvl = blockIdx.z, img = blockIdx.y;
    const float* cls = lvl == 0 ? cls0 : (lvl == 1 ? cls1 : cls2);
    const float* ctr = lvl == 0 ? ctr0 : (lvl == 1 ? ctr1 : ctr2);
    const int HW = lvl_hw(lvl);
    const int n = HW * N_CLS;
    const int p = img * 3 + lvl;
    const unsigned pre = prefix[p];
    const unsigned maskHi = (shift == 24) ? 0u : (0xFFFFFFFFu << (shift + 8));
    for (int i = threadIdx.x; i < 256; i += blockDim.x) lh[i] = 0;
    __syncthreads();
    const float* clsI = cls + (size_t)img * n;
    const float* ctrI = ctr + (size_t)img * HW;
    const int stride = gridDim.x * blockDim.x;
    for (int i = blockIdx.x * blockDim.x + threadIdx.x; i < n; i += stride) {
        float sc;
        unsigned key = score_key(clsI, ctrI, i, HW, &sc);
        if (((key ^ pre) & maskHi) == 0)
            atomicAdd(&lh[(key >> shift) & 255u], 1u);
    }
    __syncthreads();
    for (int i = threadIdx.x; i < 256; i += blockDim.x)
        if (lh[i]) atomicAdd(&hist[p * 256 + i], lh[i]);
}

__global__ void scan_k(unsigned* hist, unsigned* prefix, unsigned* kk, int shift) {
    __shared__ unsigned h[256];
    const int p = blockIdx.x;
    const int d = threadIdx.x;  // 256 threads
    h[d] = hist[p * 256 + d];
    unsigned kkp = kk[p];
    __syncthreads();
    unsigned above = 0;
    for (int j = d + 1; j < 256; j++) above += h[j];
    bool hit = (above < kkp) && ((above + h[d] >= kkp) || d == 0);
    if (hit) {
        prefix[p] |= ((unsigned)d) << shift;
        kk[p] = kkp - above;
    }
    __syncthreads();
    hist[p * 256 + d] = 0;   // ready for next round
}

__global__ void compact_k(const float* cls0, const float* cls1, const float* cls2,
                          const float* ctr0, const float* ctr1, const float* ctr2,
                          const unsigned* Tkey, const unsigned* needT,
                          unsigned* cntAny, unsigned* cntEq,
                          unsigned* candF, float* candS) {
    const int lvl = blockIdx.z, img = blockIdx.y;
    const float* cls = lvl == 0 ? cls0 : (lvl == 1 ? cls1 : cls2);
    const float* ctr = lvl == 0 ? ctr0 : (lvl == 1 ? ctr1 : ctr2);
    const int HW = lvl_hw(lvl);
    const int n = HW * N_CLS;
    const int p = img * 3 + lvl;
    const unsigned T = Tkey[p];
    const unsigned need = needT[p];
    const float* clsI = cls + (size_t)img * n;
    const float* ctrI = ctr + (size_t)img * HW;
    const int stride = gridDim.x * blockDim.x;
    for (int i = blockIdx.x * blockDim.x + threadIdx.x; i < n; i += stride) {
        float sc;
        unsigned key = score_key(clsI, ctrI, i, HW, &sc);
        if (key == 0u) continue;
        bool take = false;
        if (key > T) take = true;
        else if (key == T) {
            unsigned t = atomicAdd(&cntEq[p], 1u);
            if (t < need) take = true;
        }
        if (take) {
            unsigned slot = atomicAdd(&cntAny[p], 1u);
            if (slot < K_PRE) {
                int loc = i % HW, c = i / HW;
                candF[p * K_PRE + slot] = (unsigned)(loc * N_CLS + c);  // ref flat index
                candS[p * K_PRE + slot] = sc;
            }
        }
    }
}

__global__ void decode_k(const float* loc0, const float* loc1, const float* loc2,
                         const float* reg0, const float* reg1, const float* reg2,
                         const unsigned* candF, const float* candS,
                         float4* dbox, float* dsc, int* dcls) {
    int i = blockIdx.x * blockDim.x + threadIdx.x;
    if (i >= NPAIR * K_PRE) return;
    int p = i / K_PRE, slot = i % K_PRE;
    int img = p / 3, lvl = p % 3;
    int out = img * CAND + lvl * K_PRE + slot;
    float s = candS[i];
    if (!(s > 0.0f)) {
        dbox[out] = make_float4(0.f, 0.f, 0.f, 0.f);
        dsc[out] = -1.0f;
        dcls[out] = 0;
        return;
    }
    const float* locs = lvl == 0 ? loc0 : (lvl == 1 ? loc1 : loc2);
    const float* reg  = lvl == 0 ? reg0 : (lvl == 1 ? reg1 : reg2);
    const int HW = lvl_hw(lvl);
    const float stridef = lvl == 0 ? 8.0f : (lvl == 1 ? 16.0f : 32.0f);
    unsigned e = candF[i];
    int loc = (int)(e / N_CLS);
    int c = (int)(e % N_CLS) + 1;
    const float* r = reg + (size_t)img * 4 * HW;
    float l = r[0 * HW + loc] * stridef;
    float t = r[1 * HW + loc] * stridef;
    float rr = r[2 * HW + loc] * stridef;
    float b = r[3 * HW + loc] * stridef;
    float x = locs[loc * 2], y = locs[loc * 2 + 1];
    float x1 = fminf(fmaxf(x - l, 0.f), 800.f);
    float y1 = fminf(fmaxf(y - t, 0.f), 800.f);
    float x2 = fminf(fmaxf(x + rr, 0.f), 800.f);
    float y2 = fminf(fmaxf(y + b, 0.f), 800.f);
    dbox[out] = make_float4(x1, y1, x2, y2);
    dsc[out] = sqrtf(s);
    dcls[out] = c;
}

__global__ __launch_bounds__(256) void nms_k(const float4* dbox, const float* dsc,
                                             const int* dcls, float* out) {
    __shared__ float s[CAND];
    __shared__ float4 ob[CAND];
    __shared__ float redv[256];
    __shared__ int redi[256];
    __shared__ int pickI[K_POST];
    __shared__ float pickS[K_POST];
    const int img = blockIdx.x, tid = threadIdx.x;
    for (int j = tid; j < CAND; j += 256) {
        s[j] = dsc[img * CAND + j];
        float4 b = dbox[img * CAND + j];
        float off = (float)dcls[img * CAND + j] * 4096.0f;
        ob[j] = make_float4(b.x + off, b.y + off, b.z + off, b.w + off);
    }
    __syncthreads();
    for (int it = 0; it < K_POST; ++it) {
        float bv = -1e30f; int bi = 0x7FFFFFFF;
        for (int j = tid; j < CAND; j += 256) {
            float v = s[j];
            if (v > bv) { bv = v; bi = j; }
        }
        redv[tid] = bv; redi[tid] = bi;
        __syncthreads();
        for (int o = 128; o > 0; o >>= 1) {
            if (tid < o) {
                float v2 = redv[tid + o]; int i2 = redi[tid + o];
                if (v2 > redv[tid] || (v2 == redv[tid] && i2 < redi[tid])) {
                    redv[tid] = v2; redi[tid] = i2;
                }
            }
            __syncthreads();
        }
        int i = redi[0]; float vmax = redv[0];
        if (tid == 0) { pickI[it] = i; pickS[it] = vmax; }
        float4 bb = ob[i];
        float areaI = (bb.z - bb.x) * (bb.w - bb.y);
        __syncthreads();
        for (int j = tid; j < CAND; j += 256) {
            float4 o = ob[j];
            float xx1 = fmaxf(bb.x, o.x), yy1 = fmaxf(bb.y, o.y);
            float xx2 = fminf(bb.z, o.z), yy2 = fminf(bb.w, o.w);
            float inter = fmaxf(xx2 - xx1, 0.f) * fmaxf(yy2 - yy1, 0.f);
            float areaJ = (o.z - o.x) * (o.w - o.y);
            float iou = inter / (areaJ + areaI - inter + 1e-9f);
            if (iou > 0.6f) s[j] = -1.0f;
        }
        __syncthreads();
        if (tid == 0) s[i] = -1.0f;
        __syncthreads();
    }
    if (tid < K_POST) {
        int i = pickI[tid]; float sc = pickS[tid];
        bool keep = sc > 0.0f;
        float m = keep ? 1.0f : 0.0f;
        float4 b = dbox[img * CAND + i];
        float* bo = out + (size_t)(img * K_POST + tid) * 4;
        bo[0] = b.x * m; bo[1] = b.y * m; bo[2] = b.z * m; bo[3] = b.w * m;
        out[N_IMG * K_POST * 4 + img * K_POST + tid] = keep ? sc : 0.0f;
        out[N_IMG * K_POST * 5 + img * K_POST + tid] = keep ? (float)dcls[img * CAND + i] : 0.0f;
        out[N_IMG * K_POST * 6 + img * K_POST + tid] = m;
    }
}

extern "C" void kernel_launch(void* const* d_in, const int* in_sizes, int n_in,
                              void* d_out, int out_size, void* d_ws, size_t ws_size,
                              hipStream_t stream) {
    // setup_inputs() dict order: loc0, cls0, reg0, ctr0, loc1, cls1, reg1, ctr1, loc2, cls2, reg2, ctr2
    const float* loc0 = (const float*)d_in[0];
    const float* cls0 = (const float*)d_in[1];
    const float* reg0 = (const float*)d_in[2];
    const float* ctr0 = (const float*)d_in[3];
    const float* loc1 = (const float*)d_in[4];
    const float* cls1 = (const float*)d_in[5];
    const float* reg1 = (const float*)d_in[6];
    const float* ctr1 = (const float*)d_in[7];
    const float* loc2 = (const float*)d_in[8];
    const float* cls2 = (const float*)d_in[9];
    const float* reg2 = (const float*)d_in[10];
    const float* ctr2 = (const float*)d_in[11];

    char* ws = (char*)d_ws;
    unsigned* hist   = (unsigned*)(ws + HIST_OFF);
    unsigned* prefix = (unsigned*)(ws + PREFIX_OFF);
    unsigned* kk     = (unsigned*)(ws + KK_OFF);
    unsigned* cntAny = (unsigned*)(ws + CNTANY_OFF);
    unsigned* cntEq  = (unsigned*)(ws + CNTEQ_OFF);
    unsigned* candF  = (unsigned*)(ws + CANDF_OFF);
    float*    candS  = (float*)(ws + CANDS_OFF);
    float4*   dbox   = (float4*)(ws + DBOX_OFF);
    float*    dsc    = (float*)(ws + DSC_OFF);
    int*      dcls   = (int*)(ws + DCLS_OFF);
    float*    out    = (float*)d_out;

    init_k<<<dim3(188), 256, 0, stream>>>(hist, prefix, kk, cntAny, cntEq, candS);

    const dim3 scang(64, N_IMG, 3);
    const int shifts[4] = {24, 16, 8, 0};
    for (int r = 0; r < 4; ++r) {
        histo_k<<<scang, 256, 0, stream>>>(cls0, cls1, cls2, ctr0, ctr1, ctr2,
                                           hist, prefix, shifts[r]);
        scan_k<<<NPAIR, 256, 0, stream>>>(hist, prefix, kk, shifts[r]);
    }
    compact_k<<<scang, 256, 0, stream>>>(cls0, cls1, cls2, ctr0, ctr1, ctr2,
                                         prefix, kk, cntAny, cntEq, candF, candS);
    decode_k<<<(NPAIR * K_PRE + 255) / 256, 256, 0, stream>>>(
        loc0, loc1, loc2, reg0, reg1, reg2, candF, candS, dbox, dsc, dcls);
    nms_k<<<N_IMG, 256, 0, stream>>>(dbox, dsc, dcls, out);
}